// Round 17
// baseline (271.510 us; speedup 1.0000x reference)
//
#include <hip/hip_runtime.h>
#include <hip/hip_fp16.h>

#define NN 100000
#define NE 1600000
#define D 128
#define NC 8
#define NBUCK 391   // ceil(NN / 256) buckets of 256 node-ids
#define BCAP 6144   // fixed bucket capacity (mean 4092 -> huge margin)
#define CHUNK 4096  // edges per scatter block
#define NBLK_SC ((NE + CHUNK - 1) / CHUNK)  // 391

typedef _Float16 half8 __attribute__((ext_vector_type(8)));
typedef float f32x4 __attribute__((ext_vector_type(4)));

// ---------------- K1: bucket scatter (blocks 0..390) + weight cvt (391,392) ------
// staged[b*BCAP + pos] = src*256 | (dst&255)
__global__ __launch_bounds__(256) void k_scat(const int* __restrict__ src,
                                              const int* __restrict__ dst,
                                              int* __restrict__ bcursor,
                                              int* __restrict__ staged,
                                              const float* __restrict__ W1,
                                              __half* __restrict__ wt1,
                                              const float* __restrict__ W2,
                                              __half* __restrict__ wt2, int E) {
    const int t = threadIdx.x;
    if (blockIdx.x >= NBLK_SC) {  // wt[col][k] = half(W[k][col])
        const float* W = (blockIdx.x - NBLK_SC) ? W2 : W1;
        __half* wt = (blockIdx.x - NBLK_SC) ? wt2 : wt1;
        for (int i = t; i < D * D; i += 256) {
            int k = i >> 7, c = i & 127;
            wt[c * D + k] = __float2half(W[i]);
        }
        return;
    }
    __shared__ int h[NBUCK];
    __shared__ int cur[NBUCK];
    for (int i = t; i < NBUCK; i += 256) h[i] = 0;
    __syncthreads();
    const int base0 = blockIdx.x * CHUNK;
    int4 d4[4], s4[4];
    bool val[4];
#pragma unroll
    for (int i = 0; i < 4; ++i) {
        int e = base0 + i * 1024 + t * 4;
        val[i] = e < E;  // E % 4 == 0 -> full int4 safe
        if (val[i]) {
            d4[i] = *(const int4*)&dst[e];
            s4[i] = *(const int4*)&src[e];
            atomicAdd(&h[d4[i].x >> 8], 1);
            atomicAdd(&h[d4[i].y >> 8], 1);
            atomicAdd(&h[d4[i].z >> 8], 1);
            atomicAdd(&h[d4[i].w >> 8], 1);
        }
    }
    __syncthreads();
    for (int i = t; i < NBUCK; i += 256) {
        int c = h[i];
        cur[i] = c ? (i * BCAP + atomicAdd(&bcursor[i], c)) : 0;
    }
    __syncthreads();
#pragma unroll
    for (int i = 0; i < 4; ++i) {
        if (val[i]) {
            int p;
            p = atomicAdd(&cur[d4[i].x >> 8], 1); staged[p] = s4[i].x * 256 + (d4[i].x & 255);
            p = atomicAdd(&cur[d4[i].y >> 8], 1); staged[p] = s4[i].y * 256 + (d4[i].y & 255);
            p = atomicAdd(&cur[d4[i].z >> 8], 1); staged[p] = s4[i].z * 256 + (d4[i].z & 255);
            p = atomicAdd(&cur[d4[i].w >> 8], 1); staged[p] = s4[i].w * 256 + (d4[i].w & 255);
        }
    }
}

// ---------------- K2: per-bucket CSR build (391 blocks; r10-proven) ---------------
__global__ __launch_bounds__(256) void k_bfill(const int* __restrict__ staged,
                                               const int* __restrict__ bcursor,
                                               int* __restrict__ rowstart,
                                               int* __restrict__ cnt,
                                               float* __restrict__ dinv,
                                               int* __restrict__ csr) {
    const int b = blockIdx.x;
    const int t = threadIdx.x;
    const int bs = b * BCAP;
    const int be = bs + bcursor[b];
    __shared__ int lc[256];
    __shared__ int ls[256];
    __shared__ int sd[256];
    lc[t] = 0;
    __syncthreads();
    for (int i = bs + t; i < be; i += 256) {
        atomicAdd(&lc[staged[i] & 255], 1);
    }
    __syncthreads();
    int v = lc[t];
    sd[t] = v;
    __syncthreads();
    for (int off = 1; off < 256; off <<= 1) {
        int y = (t >= off) ? sd[t - off] : 0;
        __syncthreads();
        sd[t] += y;
        __syncthreads();
    }
    int ex = sd[t] - v;
    ls[t] = bs + ex;
    int node = (b << 8) + t;
    if (node < NN) {
        rowstart[node] = bs + ex;
        cnt[node] = v;
        dinv[node] = rsqrtf((float)(v + 1));  // +1 = self-loop
    }
    lc[t] = 0;
    __syncthreads();
    for (int i = bs + t; i < be; i += 256) {
        int e = staged[i];
        int li = e & 255;
        int p = atomicAdd(&lc[li], 1);
        csr[ls[li] + p] = e >> 8;
    }
}

// ---------------- gemm: hout[r] = half((A[r] @ W) * dinv[r]) ---------------------
// 4 waves/block; wave = 16 rows x 64 cols (4 col-tiles x 4 K-steps of 16x16x32).
template <bool F32IN>
__global__ __launch_bounds__(256) void k_gemm(const void* __restrict__ Ain,
                                              const __half* __restrict__ wt,
                                              const float* __restrict__ dinv,
                                              __half* __restrict__ hout) {
    const int tid = threadIdx.x;
    const int lane = tid & 63;
    const int wave = tid >> 6;
    const int wr = wave >> 1, wc = wave & 1;
    const int row0 = blockIdx.x * 32 + wr * 16;
    const int arow = row0 + (lane & 15);
    const int kg = lane >> 4;

    half8 afrag[4];
    if constexpr (F32IN) {
        const float* A = (const float*)Ain;
#pragma unroll
        for (int s = 0; s < 4; ++s) {
            const float* p = &A[(size_t)arow * D + s * 32 + kg * 8];
            float4 f0 = *(const float4*)p;
            float4 f1 = *(const float4*)(p + 4);
            half8 a;
            a[0] = (_Float16)f0.x; a[1] = (_Float16)f0.y;
            a[2] = (_Float16)f0.z; a[3] = (_Float16)f0.w;
            a[4] = (_Float16)f1.x; a[5] = (_Float16)f1.y;
            a[6] = (_Float16)f1.z; a[7] = (_Float16)f1.w;
            afrag[s] = a;
        }
    } else {
        const __half* A = (const __half*)Ain;
#pragma unroll
        for (int s = 0; s < 4; ++s)
            afrag[s] = *(const half8*)&A[(size_t)arow * D + s * 32 + kg * 8];
    }

    f32x4 acc[4] = {};
    const int colbase = wc * 64;
#pragma unroll
    for (int c = 0; c < 4; ++c) {
        const int col = colbase + c * 16 + (lane & 15);
#pragma unroll
        for (int s = 0; s < 4; ++s) {
            half8 b = *(const half8*)&wt[col * D + s * 32 + kg * 8];
            acc[c] = __builtin_amdgcn_mfma_f32_16x16x32_f16(afrag[s], b, acc[c], 0, 0, 0);
        }
    }

#pragma unroll
    for (int r = 0; r < 4; ++r) {
        const int row = row0 + kg * 4 + r;
        const float dv = dinv[row];
#pragma unroll
        for (int c = 0; c < 4; ++c) {
            const int col = colbase + c * 16 + (lane & 15);
            hout[(size_t)row * D + col] = __float2half(acc[c][r] * dv);
        }
    }
}

__device__ inline void add8h(float* acc, float4 raw) {
    const __half2* hp = (const __half2*)&raw;
#pragma unroll
    for (int q = 0; q < 4; ++q) {
        float2 f = __half22float2(hp[q]);
        acc[2 * q] += f.x;
        acc[2 * q + 1] += f.y;
    }
}

// ---------------- aggregation (cheap variant; r10-proven 67.5us) ------------------
// h pre-scaled by dinv[row]; gather+add; out = relu(dinv[node]*acc + bias).
// 16 lanes x 16B cover a row; 4 groups; prefetch 8 rows/pass (32 in flight/wave).
__global__ __launch_bounds__(256) void k_agg(const __half* __restrict__ hs,
                                             const int* __restrict__ rowstart,
                                             const int* __restrict__ cnt,
                                             const int* __restrict__ csr_src,
                                             const float* __restrict__ dinv,
                                             const float* __restrict__ bias,
                                             __half* __restrict__ hout) {
    const int node = blockIdx.x * 4 + (threadIdx.x >> 6);  // NN % 4 == 0, exact grid
    const int lane = threadIdx.x & 63;
    const int g = lane >> 4;           // neighbor group 0..3
    const int f8 = (lane & 15) << 3;   // feature offset (8 halves = 16B per lane)

    float acc[8] = {};
    if (g == 0) add8h(acc, *(const float4*)&hs[(size_t)node * D + f8]);  // self-loop

    const int c = cnt[node];
    const int* __restrict__ cl = csr_src + rowstart[node];

    int t = g;
    while (t < c) {
        float4 v[8];
#pragma unroll
        for (int i = 0; i < 8; ++i) {
            int tt = t + 4 * i;
            if (tt < c) {
                int s = cl[tt];
                v[i] = *(const float4*)&hs[(size_t)s * D + f8];
            }
        }
#pragma unroll
        for (int i = 0; i < 8; ++i) {
            int tt = t + 4 * i;
            if (tt < c) add8h(acc, v[i]);
        }
        t += 32;
    }

#pragma unroll
    for (int q = 0; q < 8; ++q) {
        acc[q] += __shfl_xor(acc[q], 16);
        acc[q] += __shfl_xor(acc[q], 32);
    }

    if (g == 0) {
        const float dv = dinv[node];
        float r[8];
#pragma unroll
        for (int q = 0; q < 8; ++q) r[q] = fmaxf(fmaf(dv, acc[q], bias[f8 + q]), 0.f);
        union { float4 f; __half2 h[4]; } u;
#pragma unroll
        for (int q = 0; q < 4; ++q) u.h[q] = __floats2half2_rn(r[2 * q], r[2 * q + 1]);
        *(float4*)&hout[(size_t)node * D + f8] = u.f;
    }
}

// ---------------- output: softmax(h @ Wout + bout), fp16 h ----------------
__global__ void k_out(const __half* __restrict__ h, const float* __restrict__ Wout,
                      const float* __restrict__ bout, float* __restrict__ out, int n) {
    __shared__ float ws[D * NC];
    int tid = threadIdx.x;
    for (int i = tid; i < D * NC; i += 256) ws[i] = Wout[i];
    __syncthreads();
    int node = blockIdx.x * 32 + (tid >> 3);
    int c = tid & 7;
    if (node >= n) return;
    float acc = bout[c];
    const __half* hrow = &h[(size_t)node * D];
#pragma unroll
    for (int k8 = 0; k8 < 16; ++k8) {
        float4 raw = *(const float4*)&hrow[k8 * 8];
        const __half2* hp = (const __half2*)&raw;
#pragma unroll
        for (int q = 0; q < 4; ++q) {
            float2 f = __half22float2(hp[q]);
            int k = k8 * 8 + 2 * q;
            acc += f.x * ws[k * NC + c] + f.y * ws[(k + 1) * NC + c];
        }
    }
    float m = acc;
#pragma unroll
    for (int off = 1; off < 8; off <<= 1) m = fmaxf(m, __shfl_xor(m, off));
    float e = __expf(acc - m);
    float ssum = e;
#pragma unroll
    for (int off = 1; off < 8; off <<= 1) ssum += __shfl_xor(ssum, off);
    out[(size_t)node * NC + c] = e / ssum;
}

// ---------------- launch ----------------
extern "C" void kernel_launch(void* const* d_in, const int* in_sizes, int n_in,
                              void* d_out, int out_size, void* d_ws, size_t ws_size,
                              hipStream_t stream) {
    const float* x    = (const float*)d_in[0];
    const int*   ei   = (const int*)d_in[1];   // [2][NE]: row 0 = src, row 1 = dst
    const float* W1   = (const float*)d_in[2];
    const float* b1   = (const float*)d_in[3];
    const float* W2   = (const float*)d_in[4];
    const float* b2   = (const float*)d_in[5];
    const float* Wout = (const float*)d_in[6];
    const float* bout = (const float*)d_in[7];
    float* out = (float*)d_out;

    size_t off = 0;
    char* base = (char*)d_ws;
    auto alloc = [&](size_t bytes) -> void* {
        void* p = base + off;
        off += (bytes + 255) & ~(size_t)255;
        return p;
    };
    int*    cnt      = (int*)alloc((size_t)NN * 4);
    int*    rowstart = (int*)alloc((size_t)NN * 4);
    int*    bcursor  = (int*)alloc((size_t)NBUCK * 4);
    int*    csr      = (int*)alloc((size_t)NBUCK * BCAP * 4);  // bucket-padded
    float*  dinv     = (float*)alloc((size_t)NN * 4);
    __half* wt1      = (__half*)alloc((size_t)D * D * 2);
    __half* wt2      = (__half*)alloc((size_t)D * D * 2);
    __half* h16a     = (__half*)alloc((size_t)NN * D * 2);  // gemm out (pre-scaled)
    __half* h16f     = (__half*)alloc((size_t)NN * D * 2);  // agg1 out
    __half* h16b     = (__half*)alloc((size_t)NN * D * 2);  // agg2 out
    int*    staged   = (int*)alloc((size_t)NBUCK * BCAP * 4);
    if (off > ws_size) return;  // workspace too small; fail visibly

    const int* src = ei;
    const int* dst = ei + NE;

    hipMemsetAsync(bcursor, 0, (size_t)NBUCK * 4, stream);

    // K1: bucket scatter (391 blocks) + weight cvt (2 blocks)
    k_scat<<<NBLK_SC + 2, 256, 0, stream>>>(src, dst, bcursor, staged,
                                            W1, wt1, W2, wt2, NE);
    // K2: per-bucket CSR build -> rowstart/cnt/dinv/csr
    k_bfill<<<NBUCK, 256, 0, stream>>>(staged, bcursor, rowstart, cnt, dinv, csr);

    int gemm_grid = NN / 32;   // 3125 exactly
    int agg_grid = NN / 4;     // 25000 exactly
    // layer 1: scaled gemm -> cheap agg
    k_gemm<true><<<gemm_grid, 256, 0, stream>>>(x, wt1, dinv, h16a);
    k_agg<<<agg_grid, 256, 0, stream>>>(h16a, rowstart, cnt, csr, dinv, b1, h16f);
    // layer 2: scaled gemm -> cheap agg
    k_gemm<false><<<gemm_grid, 256, 0, stream>>>(h16f, wt2, dinv, h16a);
    k_agg<<<agg_grid, 256, 0, stream>>>(h16a, rowstart, cnt, csr, dinv, b2, h16b);
    // output projection + softmax
    k_out<<<(NN + 31) / 32, 256, 0, stream>>>(h16b, Wout, bout, out, NN);
}